// Round 11
// baseline (67.228 us; speedup 1.0000x reference)
//
#include <hip/hip_runtime.h>
#include <hip/hip_bf16.h>
#include <math.h>

#define NQ   10
#define DIM  1024     // 2^NQ
#define NL   4
#define INF  512
#define OUTF 64
#define MBATCH 4096

typedef _Float16 half8 __attribute__((ext_vector_type(8)));
typedef float f32x4 __attribute__((ext_vector_type(4)));
typedef float f32x2 __attribute__((ext_vector_type(2)));

// ws layout (bytes): [0,8M) h16; [8M,12M) x16; [12M,13M) w16;
// [13M, +320) rot[40] float2; [13M+4K, +32K) tabs[4][1024] float2
#define WS_H16  0
#define WS_X16  (8u * 1024u * 1024u)
#define WS_W16  (12u * 1024u * 1024u)
#define WS_ROT  (13u * 1024u * 1024u)
#define WS_TAB  (13u * 1024u * 1024u + 4096u)

#define HD __host__ __device__

// ===========================================================================
// Compile-time GF(2) layout tracking (verified rounds 4-10).
// ===========================================================================
HD constexpr int fstep(int j, int r) {
    for (int w2 = NQ - 1; w2 >= 0; --w2) {
        const int cb = 9 - w2;
        const int tb = 9 - ((w2 + r) % NQ);
        j ^= ((j >> cb) & 1) << tb;
    }
    return j;
}
HD constexpr int ifstep(int j, int r) {
    for (int w2 = 0; w2 < NQ; ++w2) {
        const int cb = 9 - w2;
        const int tb = 9 - ((w2 + r) % NQ);
        j ^= ((j >> cb) & 1) << tb;
    }
    return j;
}
HD constexpr int sigma_fwd(int l, int x) {
    for (int t = l - 1; t >= 0; --t) x = fstep(x, t + 1);
    return x;
}
HD constexpr int sigma_inv(int l, int s) {
    for (int t = 0; t < l; ++t) s = ifstep(s, t + 1);
    return s;
}
constexpr int gate_m(int l, int b) { return sigma_fwd(l, 1 << b); }
constexpr int gate_g(int l, int b) {
    int g = 0;
    for (int j = 0; j < NQ; ++j)
        if ((sigma_inv(l, 1 << j) >> b) & 1) g |= 1 << j;
    return g;
}
struct QM { int v[NQ]; };
constexpr QM make_qm() {
    QM q{};
    for (int w = 0; w < NQ; ++w) {
        const int B = 9 - w;
        int m = 0;
        for (int j = 0; j < NQ; ++j)
            if ((sigma_inv(NL, 1 << j) >> B) & 1) m |= 1 << j;
        q.v[w] = m;
    }
    return q;
}
constexpr QM QMASKS = make_qm();

// Hardware-coordinate assignment (verified round 7): slot bits 0..2 = reg,
// WBIT = wave, remaining 6 bits = lane.
constexpr int mask_at(int t) { return gate_m(t / 10, 9 - (t % 10)); }
constexpr int pick_wbit() {
    int best = 9, bc = 1000;
    for (int j = 3; j <= 9; ++j) {
        int c = 0;
        for (int t = 0; t < 40; ++t) c += (mask_at(t) >> j) & 1;
        if (c < bc) { bc = c; best = j; }
    }
    return best;
}
constexpr int WBIT = pick_wbit();
struct LP { int v[6]; };
constexpr LP make_lpos() {
    LP p{}; int n = 0;
    for (int j = 3; j <= 9; ++j) if (j != WBIT) p.v[n++] = j;
    return p;
}
constexpr LP LPOS = make_lpos();
constexpr int lx_extract(int m) {
    int r = 0;
    for (int t = 0; t < 6; ++t) if ((m >> LPOS.v[t]) & 1) r |= 1 << t;
    return r;
}

// ===========================================================================
// Setup: blocks 0..1023 convert x->f16; 1024..1279 convert W->f16;
// block 1280: rot[40]=(cos,sin)(theta/2) + fused diagonal phase tables
// (verified rounds 8-10).
// ===========================================================================
__global__ __launch_bounds__(256) void setup_kernel(
    const float* __restrict__ x, const float* __restrict__ w,
    const float* __restrict__ qw, _Float16* __restrict__ x16,
    _Float16* __restrict__ w16, float2* __restrict__ rot,
    float2* __restrict__ tabs)
{
    const int bid = blockIdx.x;
    const int tid = threadIdx.x;
    if (bid < 1024) {
        const int base = bid * 2048 + tid * 8;
        float4 a = *reinterpret_cast<const float4*>(x + base);
        float4 b = *reinterpret_cast<const float4*>(x + base + 4);
        half8 o = {(_Float16)a.x, (_Float16)a.y, (_Float16)a.z, (_Float16)a.w,
                   (_Float16)b.x, (_Float16)b.y, (_Float16)b.z, (_Float16)b.w};
        *reinterpret_cast<half8*>(x16 + base) = o;
    } else if (bid < 1280) {
        const int base = (bid - 1024) * 2048 + tid * 8;
        float4 a = *reinterpret_cast<const float4*>(w + base);
        float4 b = *reinterpret_cast<const float4*>(w + base + 4);
        half8 o = {(_Float16)a.x, (_Float16)a.y, (_Float16)a.z, (_Float16)a.w,
                   (_Float16)b.x, (_Float16)b.y, (_Float16)b.z, (_Float16)b.w};
        *reinterpret_cast<half8*>(w16 + base) = o;
    } else {
        if (tid < NL * NQ) {
            float s, c; sincosf(0.5f * qw[tid * 3 + 1], &s, &c);
            rot[tid] = float2{c, s};
        }
        for (int u = 0; u < 4; ++u) {
            const int s_ = (tid << 2) + u;
            float a = 0.f;
            for (int w2 = 0; w2 < NQ; ++w2)
                a += qw[w2 * 3 + 0] * (((s_ >> (9 - w2)) & 1) ? 1.f : -1.f);
            float si, co; sincosf(0.5f * a, &si, &co);
            tabs[s_] = float2{co, si};
            for (int l = 0; l < 3; ++l) {
                const int j  = sigma_inv(l, s_);       // logical amp before perm_l
                const int ip = sigma_inv(l + 1, s_);   // logical amp after perm_l
                float b = 0.f;
                for (int w2 = 0; w2 < NQ; ++w2) {
                    b += qw[(l * NQ + w2) * 3 + 2]       * (((j  >> (9 - w2)) & 1) ? 1.f : -1.f);
                    b += qw[((l + 1) * NQ + w2) * 3 + 0] * (((ip >> (9 - w2)) & 1) ? 1.f : -1.f);
                }
                sincosf(0.5f * b, &si, &co);
                tabs[(l + 1) * DIM + s_] = float2{co, si};
            }
        }
    }
}

// ===========================================================================
// GEMM v2: h16 = f16(relu(x16 @ w16^T + b_pre)), mfma_f32_16x16x32_f16.
// BM=128, BN=128, BK=32, 256 threads = 4 waves (2x2), wave tile 64x64
// (4x4 fragments): 8 ds_read_b128 -> 16 MFMA per k-step (ratio 2.0 vs the
// old 1.33 — the old kernel was DS-pipe-bound at 6 reads / 8 MFMA).
// Staging pattern, LDS padding, fragment addressing, and C-write formula
// identical to the verified rounds-3..10 kernel; only indices widened.
// ===========================================================================
__global__ __launch_bounds__(256) void gemm16_kernel(
    const _Float16* __restrict__ X, const _Float16* __restrict__ W,
    const float* __restrict__ bias, _Float16* __restrict__ H)
{
    constexpr int BM = 128, BN = 128, BK = 32, LDP = BK + 8;  // 80 B rows
    __shared__ _Float16 As[BM][LDP];
    __shared__ _Float16 Bs[BN][LDP];

    const int tid = threadIdx.x;
    const int wave = tid >> 6, lane = tid & 63;
    const int wm = wave >> 1, wn = wave & 1;
    const int l15 = lane & 15, lk = (lane >> 4) * 8;

    const int arow = tid >> 1, ahalf = tid & 1;   // 128 rows x 2 halves of 16

    const _Float16* ag = X + (size_t)(blockIdx.x * BM + arow) * INF + ahalf * 16;
    const _Float16* bg = W + (size_t)(blockIdx.y * BN + arow) * INF + ahalf * 16;

    f32x4 acc[4][4] = {};

    for (int k0 = 0; k0 < INF; k0 += BK) {
        half8 av0 = *reinterpret_cast<const half8*>(ag + k0);
        half8 av1 = *reinterpret_cast<const half8*>(ag + k0 + 8);
        half8 bv0 = *reinterpret_cast<const half8*>(bg + k0);
        half8 bv1 = *reinterpret_cast<const half8*>(bg + k0 + 8);
        __syncthreads();
        *reinterpret_cast<half8*>(&As[arow][ahalf * 16])     = av0;
        *reinterpret_cast<half8*>(&As[arow][ahalf * 16 + 8]) = av1;
        *reinterpret_cast<half8*>(&Bs[arow][ahalf * 16])     = bv0;
        *reinterpret_cast<half8*>(&Bs[arow][ahalf * 16 + 8]) = bv1;
        __syncthreads();
        half8 bfr[4];
#pragma unroll
        for (int ni = 0; ni < 4; ++ni)
            bfr[ni] = *reinterpret_cast<const half8*>(&Bs[wn * 64 + ni * 16 + l15][lk]);
#pragma unroll
        for (int mi = 0; mi < 4; ++mi) {
            half8 afr = *reinterpret_cast<const half8*>(&As[wm * 64 + mi * 16 + l15][lk]);
#pragma unroll
            for (int ni = 0; ni < 4; ++ni)
                acc[mi][ni] = __builtin_amdgcn_mfma_f32_16x16x32_f16(afr, bfr[ni], acc[mi][ni], 0, 0, 0);
        }
    }

    const int crow0 = blockIdx.x * BM + wm * 64;
    const int ccol0 = blockIdx.y * BN + wn * 64;
#pragma unroll
    for (int ni = 0; ni < 4; ++ni) {
        const int col = ccol0 + ni * 16 + l15;
        const float bb = bias[col];
#pragma unroll
        for (int mi = 0; mi < 4; ++mi) {
#pragma unroll
            for (int r = 0; r < 4; ++r) {
                const int row = crow0 + mi * 16 + (lane >> 4) * 4 + r;
                const float o = fmaxf(acc[mi][ni][r] + bb, 0.f);
                H[(size_t)row * DIM + col] = (_Float16)o;
            }
        }
    }
}

// ===========================================================================
// Cross-lane xor exchange — round-4/9 routing exactly (permlane experiments
// in rounds 6 and 10 were both neutral-to-negative; closed).
// ===========================================================================
template<int MHI>
__device__ __forceinline__ int lxi(int v, int lane) {
    if constexpr (MHI == 0)
        return v;
    else if constexpr (MHI == 1)
        return __builtin_amdgcn_mov_dpp(v, 0xB1, 0xF, 0xF, false);
    else if constexpr (MHI == 2)
        return __builtin_amdgcn_mov_dpp(v, 0x4E, 0xF, 0xF, false);
    else if constexpr (MHI == 3)
        return __builtin_amdgcn_mov_dpp(v, 0x1B, 0xF, 0xF, false);
    else if constexpr (MHI == 8)
        return __builtin_amdgcn_mov_dpp(v, 0x128, 0xF, 0xF, false);
    else if constexpr (MHI < 32)
        return __builtin_amdgcn_ds_swizzle(v, 0x1F | (MHI << 10));
    else
        return __builtin_amdgcn_ds_bpermute((lane ^ MHI) << 2, v);
}

template<int MHI>
__device__ __forceinline__ float lxf(float v, int lane) {
    return __int_as_float(lxi<MHI>(__float_as_int(v), lane));
}

__device__ __forceinline__ float allred(float v, int lane) {
    v += lxf<1>(v, lane);
    v += lxf<2>(v, lane);
    v += lxf<4>(v, lane);
    v += lxf<8>(v, lane);
    v += lxf<16>(v, lane);
    v += lxf<32>(v, lane);
    return v;
}

// ===========================================================================
// RY gate (layer L, wire W): new = c*a + sign*s*p (verified rounds 8-10).
// ===========================================================================
template<int L, int W>
__device__ __forceinline__ void apply_ry(f32x2 rr[4], f32x2 ii[4],
                                         const float2* __restrict__ rot,
                                         int lane, int wave,
                                         f32x4 (*buf)[2][64])
{
    constexpr int b = 9 - W;
    constexpr int m = gate_m(L, b);
    constexpr int g = gate_g(L, b);
    constexpr int MW    = (m >> WBIT) & 1;
    constexpr int MLANE = lx_extract(m);
    constexpr int MREG  = m & 7;
    constexpr int GW    = (g >> WBIT) & 1;
    constexpr int GLANE = lx_extract(g);
    constexpr int GREG  = g & 7;

    const float2 cs = rot[L * NQ + W];   // wave-uniform -> scalar load
    int hli = __builtin_popcount(lane & GLANE) & 1;
    if constexpr (GW) hli ^= wave;
    const bool hl = hli != 0;
    const float sp = hl ? cs.y : -cs.y;
    const float sn = -sp;
    const f32x2 C = {cs.x, cs.x};

    float pr[8], pi[8];
    if constexpr (MW == 0) {
#pragma unroll
        for (int k = 0; k < 8; ++k) {
            const int kp = k ^ MREG;
            const float vr = (kp & 1) ? rr[kp >> 1].y : rr[kp >> 1].x;
            const float vi = (kp & 1) ? ii[kp >> 1].y : ii[kp >> 1].x;
            pr[k] = lxf<MLANE>(vr, lane);
            pi[k] = lxf<MLANE>(vi, lane);
        }
    } else {
        buf[0][wave][lane] = f32x4{rr[0].x, rr[0].y, rr[1].x, rr[1].y};
        buf[1][wave][lane] = f32x4{rr[2].x, rr[2].y, rr[3].x, rr[3].y};
        buf[2][wave][lane] = f32x4{ii[0].x, ii[0].y, ii[1].x, ii[1].y};
        buf[3][wave][lane] = f32x4{ii[2].x, ii[2].y, ii[3].x, ii[3].y};
        __syncthreads();
        const int pl = lane ^ MLANE;
        const int pw = wave ^ 1;
        const f32x4 R0 = buf[0][pw][pl];
        const f32x4 R1 = buf[1][pw][pl];
        const f32x4 I0 = buf[2][pw][pl];
        const f32x4 I1 = buf[3][pw][pl];
        __syncthreads();
#pragma unroll
        for (int k = 0; k < 8; ++k) {
            const int kp = k ^ MREG;
            pr[k] = (kp & 4) ? R1[kp & 3] : R0[kp & 3];
            pi[k] = (kp & 4) ? I1[kp & 3] : I0[kp & 3];
        }
    }
#pragma unroll
    for (int j = 0; j < 4; ++j) {
        const int k0 = 2 * j, k1 = 2 * j + 1;
        const float s0 = (__builtin_popcount(k0 & GREG) & 1) ? sn : sp;
        const float s1 = (__builtin_popcount(k1 & GREG) & 1) ? sn : sp;
        const f32x2 S = {s0, s1};
        const f32x2 PR = {pr[k0], pr[k1]};
        const f32x2 PI = {pi[k0], pi[k1]};
        rr[j] = C * rr[j] + S * PR;
        ii[j] = C * ii[j] + S * PI;
    }
}

// fused diagonal from preloaded registers (prefetched a layer early)
__device__ __forceinline__ void apply_diag_reg(f32x2 rr[4], f32x2 ii[4],
                                               const f32x4 d[4])
{
#pragma unroll
    for (int j = 0; j < 4; ++j) {
        const f32x2 CR = {d[j].x, d[j].z};
        const f32x2 CI = {d[j].y, d[j].w};
        const f32x2 R = rr[j], I = ii[j];
        rr[j] = R * CR - I * CI;
        ii[j] = I * CR + R * CI;
    }
}

template<int L>
__device__ __forceinline__ void apply_layer(f32x2 rr[4], f32x2 ii[4],
                                            const float2* __restrict__ rot,
                                            int lane, int wave,
                                            f32x4 (*buf)[2][64])
{
    apply_ry<L, 0>(rr, ii, rot, lane, wave, buf);
    apply_ry<L, 1>(rr, ii, rot, lane, wave, buf);
    apply_ry<L, 2>(rr, ii, rot, lane, wave, buf);
    apply_ry<L, 3>(rr, ii, rot, lane, wave, buf);
    apply_ry<L, 4>(rr, ii, rot, lane, wave, buf);
    apply_ry<L, 5>(rr, ii, rot, lane, wave, buf);
    apply_ry<L, 6>(rr, ii, rot, lane, wave, buf);
    apply_ry<L, 7>(rr, ii, rot, lane, wave, buf);
    apply_ry<L, 8>(rr, ii, rot, lane, wave, buf);
    apply_ry<L, 9>(rr, ii, rot, lane, wave, buf);
}

// ===========================================================================
// Quantum kernel: 2 waves/row, 8 amps/thread (rounds 7-10 shape). Diag
// tables prefetched one layer ahead (round 9). Routing = round 9 exactly.
// ===========================================================================
__global__ __launch_bounds__(128, 8) void quantum_kernel(
    const _Float16* __restrict__ Hbuf, const float2* __restrict__ rot,
    const float2* __restrict__ tabs, const float* __restrict__ W_post,
    const float* __restrict__ b_post, float* __restrict__ out)
{
    __shared__ f32x4 buf[4][2][64];
    __shared__ float sred[34];

    const int lane = threadIdx.x;
    const int wave = threadIdx.y;
    const int row  = blockIdx.x;

    int pb = wave << WBIT;
#pragma unroll
    for (int t = 0; t < 6; ++t) pb |= ((lane >> t) & 1) << LPOS.v[t];

    const f32x4* t0 = reinterpret_cast<const f32x4*>(tabs + pb);
    const f32x4* t1 = reinterpret_cast<const f32x4*>(tabs + 1 * DIM + pb);
    const f32x4* t2 = reinterpret_cast<const f32x4*>(tabs + 2 * DIM + pb);
    const f32x4* t3 = reinterpret_cast<const f32x4*>(tabs + 3 * DIM + pb);

    // --- load 8 real amps (f16) + initial diag table
    const _Float16* hr = Hbuf + (size_t)row * DIM + pb;
    f32x2 A[4];
    f32x4 d[4];
    {
        half8 h0 = *reinterpret_cast<const half8*>(hr);
#pragma unroll
        for (int j = 0; j < 4; ++j) {
            A[j] = f32x2{(float)h0[2 * j], (float)h0[2 * j + 1]};
            d[j] = t0[j];
        }
    }

    // --- squared norm (phases preserve it)
    f32x2 n2 = f32x2{0.f, 0.f};
#pragma unroll
    for (int j = 0; j < 4; ++j) n2 += A[j] * A[j];
    float nw = allred(n2.x + n2.y, lane);
    if (lane == 0) sred[32 + wave] = nw;
    __syncthreads();
    const float inv_nrm = 1.0f / (sred[32] + sred[33]);

    // --- initial RZ(phi_0) phases applied to real state
    f32x2 rr[4], ii[4];
#pragma unroll
    for (int j = 0; j < 4; ++j) {
        rr[j] = A[j] * f32x2{d[j].x, d[j].z};
        ii[j] = A[j] * f32x2{d[j].y, d[j].w};
    }

    // --- circuit: prefetch next diag, run RY layer, apply diag
#pragma unroll
    for (int j = 0; j < 4; ++j) d[j] = t1[j];
    apply_layer<0>(rr, ii, rot, lane, wave, buf);
    apply_diag_reg(rr, ii, d);
#pragma unroll
    for (int j = 0; j < 4; ++j) d[j] = t2[j];
    apply_layer<1>(rr, ii, rot, lane, wave, buf);
    apply_diag_reg(rr, ii, d);
#pragma unroll
    for (int j = 0; j < 4; ++j) d[j] = t3[j];
    apply_layer<2>(rr, ii, rot, lane, wave, buf);
    apply_diag_reg(rr, ii, d);
    apply_layer<3>(rr, ii, rot, lane, wave, buf);
    // final diagonal + perm dropped: |psi|^2 invariant; QMASKS handles layout.

    // --- probabilities
    f32x2 P[4];
#pragma unroll
    for (int j = 0; j < 4; ++j) P[j] = rr[j] * rr[j] + ii[j] * ii[j];

    // --- PauliZ expvals with layout-adjusted sign masks
    float z[NQ];
#pragma unroll
    for (int w = 0; w < NQ; ++w) {
        const int q = QMASKS.v[w];
        const int qw_ = (q >> WBIT) & 1;
        const int qlane = lx_extract(q);
        const int qreg = q & 7;
        float zl = 0.f;
#pragma unroll
        for (int j = 0; j < 4; ++j) {
            const float s0 = (__builtin_popcount((2 * j) & qreg) & 1) ? -1.f : 1.f;
            const float s1 = (__builtin_popcount((2 * j + 1) & qreg) & 1) ? -1.f : 1.f;
            zl += s0 * P[j].x + s1 * P[j].y;
        }
        int neg = __builtin_popcount(lane & qlane) & 1;
        neg ^= (wave & qw_);
        if (neg) zl = -zl;
        z[w] = allred(zl, lane);
    }
    if (lane == 0) {
#pragma unroll
        for (int w = 0; w < NQ; ++w) sred[wave * 16 + w] = z[w];
    }
    __syncthreads();

    // --- post-GEMM (wave 0): out[row*64 + lane]
    if (wave == 0) {
        float o = b_post[lane];
#pragma unroll
        for (int w = 0; w < NQ; ++w)
            o = fmaf((sred[w] + sred[16 + w]) * inv_nrm, W_post[lane * NQ + w], o);
        out[(size_t)row * OUTF + lane] = o;
    }
}

extern "C" void kernel_launch(void* const* d_in, const int* in_sizes, int n_in,
                              void* d_out, int out_size, void* d_ws, size_t ws_size,
                              hipStream_t stream) {
    const float* x      = (const float*)d_in[0];
    const float* W_pre  = (const float*)d_in[1];
    const float* b_pre  = (const float*)d_in[2];
    const float* qw     = (const float*)d_in[3];
    const float* W_post = (const float*)d_in[4];
    const float* b_post = (const float*)d_in[5];
    float* out = (float*)d_out;

    char* ws = (char*)d_ws;
    _Float16* h16 = (_Float16*)(ws + WS_H16);
    _Float16* x16 = (_Float16*)(ws + WS_X16);
    _Float16* w16 = (_Float16*)(ws + WS_W16);
    float2*   rot = (float2*)  (ws + WS_ROT);
    float2*   tabs= (float2*)  (ws + WS_TAB);

    setup_kernel<<<1281, 256, 0, stream>>>(x, W_pre, qw, x16, w16, rot, tabs);
    dim3 g1(MBATCH / 128, DIM / 128);
    gemm16_kernel<<<g1, 256, 0, stream>>>(x16, w16, b_pre, h16);
    quantum_kernel<<<MBATCH, dim3(64, 2), 0, stream>>>(h16, rot, tabs, W_post, b_post, out);
}

// Round 12
// 63.486 us; speedup vs baseline: 1.0590x; 1.0590x over previous
//
#include <hip/hip_runtime.h>
#include <hip/hip_bf16.h>
#include <math.h>

#define NQ   10
#define DIM  1024     // 2^NQ
#define NL   4
#define INF  512
#define OUTF 64
#define MBATCH 4096

typedef _Float16 half8 __attribute__((ext_vector_type(8)));
typedef float f32x4 __attribute__((ext_vector_type(4)));
typedef float f32x2 __attribute__((ext_vector_type(2)));

// ws layout (bytes): [0,8M) h16; [8M,12M) x16; [12M,13M) w16;
// [13M, +320) rot[40] float2; [13M+4K, +32K) tabs[4][1024] float2
#define WS_H16  0
#define WS_X16  (8u * 1024u * 1024u)
#define WS_W16  (12u * 1024u * 1024u)
#define WS_ROT  (13u * 1024u * 1024u)
#define WS_TAB  (13u * 1024u * 1024u + 4096u)

#define HD __host__ __device__

// ===========================================================================
// Compile-time GF(2) layout tracking (verified rounds 4-11).
// ===========================================================================
HD constexpr int fstep(int j, int r) {
    for (int w2 = NQ - 1; w2 >= 0; --w2) {
        const int cb = 9 - w2;
        const int tb = 9 - ((w2 + r) % NQ);
        j ^= ((j >> cb) & 1) << tb;
    }
    return j;
}
HD constexpr int ifstep(int j, int r) {
    for (int w2 = 0; w2 < NQ; ++w2) {
        const int cb = 9 - w2;
        const int tb = 9 - ((w2 + r) % NQ);
        j ^= ((j >> cb) & 1) << tb;
    }
    return j;
}
HD constexpr int sigma_fwd(int l, int x) {
    for (int t = l - 1; t >= 0; --t) x = fstep(x, t + 1);
    return x;
}
HD constexpr int sigma_inv(int l, int s) {
    for (int t = 0; t < l; ++t) s = ifstep(s, t + 1);
    return s;
}
constexpr int gate_m(int l, int b) { return sigma_fwd(l, 1 << b); }
constexpr int gate_g(int l, int b) {
    int g = 0;
    for (int j = 0; j < NQ; ++j)
        if ((sigma_inv(l, 1 << j) >> b) & 1) g |= 1 << j;
    return g;
}
struct QM { int v[NQ]; };
constexpr QM make_qm() {
    QM q{};
    for (int w = 0; w < NQ; ++w) {
        const int B = 9 - w;
        int m = 0;
        for (int j = 0; j < NQ; ++j)
            if ((sigma_inv(NL, 1 << j) >> B) & 1) m |= 1 << j;
        q.v[w] = m;
    }
    return q;
}
constexpr QM QMASKS = make_qm();

// ===========================================================================
// Setup: blocks 0..1023 convert x->f16; 1024..1279 convert W->f16;
// block 1280: rot[40]=(cos,sin)(theta/2) + fused diagonal phase tables
// (verified rounds 8-11).  Slot index = physical storage index (identity
// mapping to (lane<<4)|k in the quantum kernel).
// ===========================================================================
__global__ __launch_bounds__(256) void setup_kernel(
    const float* __restrict__ x, const float* __restrict__ w,
    const float* __restrict__ qw, _Float16* __restrict__ x16,
    _Float16* __restrict__ w16, float2* __restrict__ rot,
    float2* __restrict__ tabs)
{
    const int bid = blockIdx.x;
    const int tid = threadIdx.x;
    if (bid < 1024) {
        const int base = bid * 2048 + tid * 8;
        float4 a = *reinterpret_cast<const float4*>(x + base);
        float4 b = *reinterpret_cast<const float4*>(x + base + 4);
        half8 o = {(_Float16)a.x, (_Float16)a.y, (_Float16)a.z, (_Float16)a.w,
                   (_Float16)b.x, (_Float16)b.y, (_Float16)b.z, (_Float16)b.w};
        *reinterpret_cast<half8*>(x16 + base) = o;
    } else if (bid < 1280) {
        const int base = (bid - 1024) * 2048 + tid * 8;
        float4 a = *reinterpret_cast<const float4*>(w + base);
        float4 b = *reinterpret_cast<const float4*>(w + base + 4);
        half8 o = {(_Float16)a.x, (_Float16)a.y, (_Float16)a.z, (_Float16)a.w,
                   (_Float16)b.x, (_Float16)b.y, (_Float16)b.z, (_Float16)b.w};
        *reinterpret_cast<half8*>(w16 + base) = o;
    } else {
        if (tid < NL * NQ) {
            float s, c; sincosf(0.5f * qw[tid * 3 + 1], &s, &c);
            rot[tid] = float2{c, s};
        }
        for (int u = 0; u < 4; ++u) {
            const int s_ = (tid << 2) + u;
            float a = 0.f;
            for (int w2 = 0; w2 < NQ; ++w2)
                a += qw[w2 * 3 + 0] * (((s_ >> (9 - w2)) & 1) ? 1.f : -1.f);
            float si, co; sincosf(0.5f * a, &si, &co);
            tabs[s_] = float2{co, si};
            for (int l = 0; l < 3; ++l) {
                const int j  = sigma_inv(l, s_);       // logical amp before perm_l
                const int ip = sigma_inv(l + 1, s_);   // logical amp after perm_l
                float b = 0.f;
                for (int w2 = 0; w2 < NQ; ++w2) {
                    b += qw[(l * NQ + w2) * 3 + 2]       * (((j  >> (9 - w2)) & 1) ? 1.f : -1.f);
                    b += qw[((l + 1) * NQ + w2) * 3 + 0] * (((ip >> (9 - w2)) & 1) ? 1.f : -1.f);
                }
                sincosf(0.5f * b, &si, &co);
                tabs[(l + 1) * DIM + s_] = float2{co, si};
            }
        }
    }
}

// ===========================================================================
// GEMM: h16 = f16(relu(x16 @ w16^T + b_pre)) via mfma_f32_16x16x32_f16
// (rounds 3-10 verified version, BM=128 BN=64 — 512 blocks = 2/CU; the
// round-11 128x128 retile at 1 block/CU was neutral-to-negative, reverted).
// ===========================================================================
__global__ __launch_bounds__(256) void gemm16_kernel(
    const _Float16* __restrict__ X, const _Float16* __restrict__ W,
    const float* __restrict__ bias, _Float16* __restrict__ H)
{
    constexpr int BM = 128, BN = 64, BK = 32, LDP = BK + 8;
    __shared__ _Float16 As[BM][LDP];
    __shared__ _Float16 Bs[BN][LDP];

    const int tid = threadIdx.x;
    const int wave = tid >> 6, lane = tid & 63;
    const int wm = wave >> 1, wn = wave & 1;
    const int l15 = lane & 15, lk = (lane >> 4) * 8;

    const int arow = tid >> 1, ahalf = tid & 1;
    const int brow = tid & 63, bseg = tid >> 6;

    const _Float16* ag = X + (size_t)(blockIdx.x * BM + arow) * INF + ahalf * 16;
    const _Float16* bg = W + (size_t)(blockIdx.y * BN + brow) * INF + bseg * 8;

    f32x4 acc[4][2] = {};

    for (int k0 = 0; k0 < INF; k0 += BK) {
        half8 av0 = *reinterpret_cast<const half8*>(ag + k0);
        half8 av1 = *reinterpret_cast<const half8*>(ag + k0 + 8);
        half8 bv  = *reinterpret_cast<const half8*>(bg + k0);
        __syncthreads();
        *reinterpret_cast<half8*>(&As[arow][ahalf * 16])     = av0;
        *reinterpret_cast<half8*>(&As[arow][ahalf * 16 + 8]) = av1;
        *reinterpret_cast<half8*>(&Bs[brow][bseg * 8])       = bv;
        __syncthreads();
        half8 bfr0 = *reinterpret_cast<const half8*>(&Bs[wn * 32 + l15][lk]);
        half8 bfr1 = *reinterpret_cast<const half8*>(&Bs[wn * 32 + 16 + l15][lk]);
#pragma unroll
        for (int mi = 0; mi < 4; ++mi) {
            half8 afr = *reinterpret_cast<const half8*>(&As[wm * 64 + mi * 16 + l15][lk]);
            acc[mi][0] = __builtin_amdgcn_mfma_f32_16x16x32_f16(afr, bfr0, acc[mi][0], 0, 0, 0);
            acc[mi][1] = __builtin_amdgcn_mfma_f32_16x16x32_f16(afr, bfr1, acc[mi][1], 0, 0, 0);
        }
    }

    const int crow0 = blockIdx.x * BM + wm * 64;
    const int ccol0 = blockIdx.y * BN + wn * 32;
#pragma unroll
    for (int ni = 0; ni < 2; ++ni) {
        const int col = ccol0 + ni * 16 + l15;
        const float bb = bias[col];
#pragma unroll
        for (int mi = 0; mi < 4; ++mi) {
#pragma unroll
            for (int r = 0; r < 4; ++r) {
                const int row = crow0 + mi * 16 + (lane >> 4) * 4 + r;
                const float o = fmaxf(acc[mi][ni][r] + bb, 0.f);
                H[(size_t)row * DIM + col] = (_Float16)o;
            }
        }
    }
}

// ===========================================================================
// Cross-lane xor exchange — round-4/9 routing exactly (permlane experiments
// closed: neutral-to-negative in rounds 6 and 10).
// ===========================================================================
template<int MHI>
__device__ __forceinline__ int lxi(int v, int lane) {
    if constexpr (MHI == 0)
        return v;
    else if constexpr (MHI == 1)
        return __builtin_amdgcn_mov_dpp(v, 0xB1, 0xF, 0xF, false);
    else if constexpr (MHI == 2)
        return __builtin_amdgcn_mov_dpp(v, 0x4E, 0xF, 0xF, false);
    else if constexpr (MHI == 3)
        return __builtin_amdgcn_mov_dpp(v, 0x1B, 0xF, 0xF, false);
    else if constexpr (MHI == 8)
        return __builtin_amdgcn_mov_dpp(v, 0x128, 0xF, 0xF, false);
    else if constexpr (MHI < 32)
        return __builtin_amdgcn_ds_swizzle(v, 0x1F | (MHI << 10));
    else
        return __builtin_amdgcn_ds_bpermute((lane ^ MHI) << 2, v);
}

template<int MHI>
__device__ __forceinline__ float lxf(float v, int lane) {
    return __int_as_float(lxi<MHI>(__float_as_int(v), lane));
}

__device__ __forceinline__ float allred(float v, int lane) {
    v += lxf<1>(v, lane);
    v += lxf<2>(v, lane);
    v += lxf<4>(v, lane);
    v += lxf<8>(v, lane);
    v += lxf<16>(v, lane);
    v += lxf<32>(v, lane);
    return v;
}

// ===========================================================================
// RY gate (layer L, wire W) on the round-4 layout: ONE wave per row,
// 16 amps/thread, slot = (lane<<4) | k.  No LDS, no barriers, no
// cross-wave path.  new = c*a + sign*s*partner, sign=+ iff logical bit=1
// (sign algebra verified rounds 8-11).
// ===========================================================================
template<int L, int W>
__device__ __forceinline__ void apply_ry(f32x2 rr[8], f32x2 ii[8],
                                         const float2* __restrict__ rot,
                                         int lane)
{
    constexpr int b = 9 - W;
    constexpr int m = gate_m(L, b);
    constexpr int g = gate_g(L, b);
    constexpr int MHI = m >> 4, MLO = m & 15;
    constexpr int GHI = g >> 4, GLO = g & 15;

    const float2 cs = rot[L * NQ + W];   // wave-uniform -> scalar load
    const bool hl = (__builtin_popcount(lane & GHI) & 1) != 0;
    const float sp = hl ? cs.y : -cs.y;
    const float sn = -sp;
    const f32x2 C = {cs.x, cs.x};

    float pr[16], pi[16];
#pragma unroll
    for (int k = 0; k < 16; ++k) {
        const int kp = k ^ MLO;
        const float vr = (kp & 1) ? rr[kp >> 1].y : rr[kp >> 1].x;
        const float vi = (kp & 1) ? ii[kp >> 1].y : ii[kp >> 1].x;
        pr[k] = lxf<MHI>(vr, lane);
        pi[k] = lxf<MHI>(vi, lane);
    }
#pragma unroll
    for (int j = 0; j < 8; ++j) {
        const int k0 = 2 * j, k1 = 2 * j + 1;
        const float s0 = (__builtin_popcount(k0 & GLO) & 1) ? sn : sp;   // compile-time pick
        const float s1 = (__builtin_popcount(k1 & GLO) & 1) ? sn : sp;
        const f32x2 S = {s0, s1};
        const f32x2 PR = {pr[k0], pr[k1]};
        const f32x2 PI = {pi[k0], pi[k1]};
        rr[j] = C * rr[j] + S * PR;
        ii[j] = C * ii[j] + S * PI;
    }
}

// fused diagonal from preloaded registers (prefetched a layer early)
__device__ __forceinline__ void apply_diag_reg(f32x2 rr[8], f32x2 ii[8],
                                               const f32x4 d[8])
{
#pragma unroll
    for (int j = 0; j < 8; ++j) {
        const f32x2 CR = {d[j].x, d[j].z};
        const f32x2 CI = {d[j].y, d[j].w};
        const f32x2 R = rr[j], I = ii[j];
        rr[j] = R * CR - I * CI;
        ii[j] = I * CR + R * CI;
    }
}

template<int L>
__device__ __forceinline__ void apply_layer(f32x2 rr[8], f32x2 ii[8],
                                            const float2* __restrict__ rot,
                                            int lane)
{
    apply_ry<L, 0>(rr, ii, rot, lane);
    apply_ry<L, 1>(rr, ii, rot, lane);
    apply_ry<L, 2>(rr, ii, rot, lane);
    apply_ry<L, 3>(rr, ii, rot, lane);
    apply_ry<L, 4>(rr, ii, rot, lane);
    apply_ry<L, 5>(rr, ii, rot, lane);
    apply_ry<L, 6>(rr, ii, rot, lane);
    apply_ry<L, 7>(rr, ii, rot, lane);
    apply_ry<L, 8>(rr, ii, rot, lane);
    apply_ry<L, 9>(rr, ii, rot, lane);
}

// ===========================================================================
// Quantum kernel: round-4 structure (best bench total) + round-8 RY math.
// ONE wave per row, 4 rows per 256-thread block, 16 amps/thread, zero LDS,
// zero barriers.  Diag tables prefetched one layer ahead (round 9).
// ===========================================================================
__global__ __launch_bounds__(256) void quantum_kernel(
    const _Float16* __restrict__ Hbuf, const float2* __restrict__ rot,
    const float2* __restrict__ tabs, const float* __restrict__ W_post,
    const float* __restrict__ b_post, float* __restrict__ out)
{
    const int lane = threadIdx.x;                    // 0..63
    const int row  = blockIdx.x * 4 + threadIdx.y;   // batch row

    const int pb = lane << 4;                        // slot base (identity map)
    const f32x4* t0 = reinterpret_cast<const f32x4*>(tabs + pb);
    const f32x4* t1 = reinterpret_cast<const f32x4*>(tabs + 1 * DIM + pb);
    const f32x4* t2 = reinterpret_cast<const f32x4*>(tabs + 2 * DIM + pb);
    const f32x4* t3 = reinterpret_cast<const f32x4*>(tabs + 3 * DIM + pb);

    // --- load 16 real amps (f16) + initial diag table
    const _Float16* hr = Hbuf + (size_t)row * DIM + pb;
    f32x2 A[8];
    f32x4 d[8];
    {
        half8 h0 = *reinterpret_cast<const half8*>(hr);
        half8 h1 = *reinterpret_cast<const half8*>(hr + 8);
#pragma unroll
        for (int j = 0; j < 4; ++j) {
            A[j]     = f32x2{(float)h0[2 * j], (float)h0[2 * j + 1]};
            A[j + 4] = f32x2{(float)h1[2 * j], (float)h1[2 * j + 1]};
        }
#pragma unroll
        for (int j = 0; j < 8; ++j) d[j] = t0[j];
    }

    // --- squared norm (phases preserve it)
    f32x2 n2 = f32x2{0.f, 0.f};
#pragma unroll
    for (int j = 0; j < 8; ++j) n2 += A[j] * A[j];
    const float inv_nrm = 1.0f / allred(n2.x + n2.y, lane);

    // --- initial RZ(phi_0) phases applied to real state
    f32x2 rr[8], ii[8];
#pragma unroll
    for (int j = 0; j < 8; ++j) {
        rr[j] = A[j] * f32x2{d[j].x, d[j].z};
        ii[j] = A[j] * f32x2{d[j].y, d[j].w};
    }

    // --- circuit: prefetch next diag, run RY layer, apply diag
#pragma unroll
    for (int j = 0; j < 8; ++j) d[j] = t1[j];
    apply_layer<0>(rr, ii, rot, lane);
    apply_diag_reg(rr, ii, d);
#pragma unroll
    for (int j = 0; j < 8; ++j) d[j] = t2[j];
    apply_layer<1>(rr, ii, rot, lane);
    apply_diag_reg(rr, ii, d);
#pragma unroll
    for (int j = 0; j < 8; ++j) d[j] = t3[j];
    apply_layer<2>(rr, ii, rot, lane);
    apply_diag_reg(rr, ii, d);
    apply_layer<3>(rr, ii, rot, lane);
    // final diagonal + perm dropped: |psi|^2 invariant; QMASKS handles layout.

    // --- probabilities
    f32x2 P[8];
#pragma unroll
    for (int j = 0; j < 8; ++j) P[j] = rr[j] * rr[j] + ii[j] * ii[j];

    // --- PauliZ expvals with layout-adjusted sign masks
    float z[NQ];
#pragma unroll
    for (int w = 0; w < NQ; ++w) {
        const int q = QMASKS.v[w];
        const int qhi = q >> 4, qlo = q & 15;
        float zl = 0.f;
#pragma unroll
        for (int j = 0; j < 8; ++j) {
            const float s0 = (__builtin_popcount((2 * j) & qlo) & 1) ? -1.f : 1.f;
            const float s1 = (__builtin_popcount((2 * j + 1) & qlo) & 1) ? -1.f : 1.f;
            zl += s0 * P[j].x + s1 * P[j].y;
        }
        if (__builtin_popcount(lane & qhi) & 1) zl = -zl;
        z[w] = allred(zl, lane) * inv_nrm;
    }

    // --- post-GEMM: out[row*64 + lane]
    float o = b_post[lane];
#pragma unroll
    for (int w = 0; w < NQ; ++w)
        o = fmaf(z[w], W_post[lane * NQ + w], o);
    out[(size_t)row * OUTF + lane] = o;
}

extern "C" void kernel_launch(void* const* d_in, const int* in_sizes, int n_in,
                              void* d_out, int out_size, void* d_ws, size_t ws_size,
                              hipStream_t stream) {
    const float* x      = (const float*)d_in[0];
    const float* W_pre  = (const float*)d_in[1];
    const float* b_pre  = (const float*)d_in[2];
    const float* qw     = (const float*)d_in[3];
    const float* W_post = (const float*)d_in[4];
    const float* b_post = (const float*)d_in[5];
    float* out = (float*)d_out;

    char* ws = (char*)d_ws;
    _Float16* h16 = (_Float16*)(ws + WS_H16);
    _Float16* x16 = (_Float16*)(ws + WS_X16);
    _Float16* w16 = (_Float16*)(ws + WS_W16);
    float2*   rot = (float2*)  (ws + WS_ROT);
    float2*   tabs= (float2*)  (ws + WS_TAB);

    setup_kernel<<<1281, 256, 0, stream>>>(x, W_pre, qw, x16, w16, rot, tabs);
    dim3 g1(MBATCH / 128, DIM / 64);
    gemm16_kernel<<<g1, 256, 0, stream>>>(x16, w16, b_pre, h16);
    quantum_kernel<<<MBATCH / 4, dim3(64, 4), 0, stream>>>(h16, rot, tabs, W_post, b_post, out);
}